// Round 1
// baseline (594.986 us; speedup 1.0000x reference)
//
#include <hip/hip_runtime.h>

typedef __attribute__((ext_vector_type(8))) short short8;
typedef __attribute__((ext_vector_type(4))) float float4v;

#define V_ 20000
#define KS 8
#define MPAD 3328

__device__ __forceinline__ unsigned short f2bf(float f) {
    union { float f; unsigned int u; } v; v.f = f;
    unsigned int u = v.u;
    u += 0x7fffu + ((u >> 16) & 1u);
    return (unsigned short)(u >> 16);
}

__device__ __forceinline__ float fast_tanh(float x) {
    float xc = fminf(15.f, fmaxf(-15.f, x));
    float e = __expf(2.f * xc);
    return (e - 1.f) / (e + 1.f);   // tanh(0) == 0 exactly (mask depends on it)
}

__device__ __forceinline__ float sigmoidf_(float x) {
    float xc = fminf(30.f, fmaxf(-30.f, x));
    return 1.f / (1.f + __expf(-xc));
}

// ---------------------------------------------------------------- cvt emb -> bf16 transposed [128n][20000k]
__global__ __launch_bounds__(256) void cvt_embT(const float* __restrict__ emb,
                                                unsigned short* __restrict__ embT) {
    __shared__ unsigned short tile[128 * 65];
    int tid = threadIdx.x;
    int k0 = blockIdx.x * 64;
    const float4v* e4 = (const float4v*)emb;
    #pragma unroll
    for (int c = 0; c < 8; ++c) {
        int l4 = c * 256 + tid;      // float4 index in 64k x 128n tile
        int k = l4 >> 5;             // 32 float4 per k-row
        int n4 = l4 & 31;
        float4v f = {0.f, 0.f, 0.f, 0.f};
        if (k0 + k < V_) f = e4[(size_t)(k0 + k) * 32 + n4];
        tile[(n4 * 4 + 0) * 65 + k] = f2bf(f.x);
        tile[(n4 * 4 + 1) * 65 + k] = f2bf(f.y);
        tile[(n4 * 4 + 2) * 65 + k] = f2bf(f.z);
        tile[(n4 * 4 + 3) * 65 + k] = f2bf(f.w);
    }
    __syncthreads();
    #pragma unroll
    for (int c = 0; c < 4; ++c) {
        int l8 = c * 256 + tid;      // n*8 + seg
        int n = l8 >> 3, seg = l8 & 7;
        int kk = k0 + seg * 8;
        if (kk < V_) {
            short8 v;
            #pragma unroll
            for (int i = 0; i < 8; ++i) v[i] = (short)tile[n * 65 + seg * 8 + i];
            *(short8*)(embT + (size_t)n * V_ + kk) = v;
        }
    }
}

// ---------------------------------------------------------------- big GEMM: partial[ks][3328][128] = rows @ emb
// rows 0..3199 = x, 3200..3231 = a, rest padding
__global__ __launch_bounds__(256) void big_gemm(const float* __restrict__ x,
                                                const float* __restrict__ a,
                                                const unsigned short* __restrict__ embT,
                                                float* __restrict__ partial) {
    __shared__ unsigned short Alds[128 * 40];   // [row][k] pad stride 40
    __shared__ unsigned short Blds[128 * 40];   // [n][k]   pad stride 40
    int tid = threadIdx.x;
    int bx = blockIdx.x, by = blockIdx.y;
    int m0 = bx * 128;
    // split 625 k-blocks (of 32) across KS slices
    const int per = 625 / KS, extra = 625 % KS;
    int kb0 = by * per + (by < extra ? by : extra);
    int nkb = per + (by < extra ? 1 : 0);

    int lane = tid & 63, wave = tid >> 6;
    int wr = wave >> 1, wc = wave & 1;
    int ln = lane & 15, quad = lane >> 4;

    float4v acc[4][4];
    #pragma unroll
    for (int i = 0; i < 4; ++i)
        #pragma unroll
        for (int j = 0; j < 4; ++j) acc[i][j] = (float4v){0.f, 0.f, 0.f, 0.f};

    int row = tid >> 1, seg = tid & 1;
    int rg = m0 + row;
    int aidx = rg - 3200; if (aidx < 0) aidx = 0; if (aidx > 31) aidx = 31;
    const float* __restrict__ srcA = (rg < 3200) ? (x + (size_t)rg * V_)
                                                 : (a + (size_t)aidx * V_);
    const unsigned short* __restrict__ srcB = embT + (size_t)row * V_;

    for (int it = 0; it < nkb; ++it) {
        int k0 = (kb0 + it) * 32;
        // stage A: 16 floats/thread -> bf16
        const float4v* ap = (const float4v*)(srcA + k0 + seg * 16);
        float4v f0 = ap[0], f1 = ap[1], f2 = ap[2], f3 = ap[3];
        short8 w0, w1;
        w0[0]=(short)f2bf(f0.x); w0[1]=(short)f2bf(f0.y); w0[2]=(short)f2bf(f0.z); w0[3]=(short)f2bf(f0.w);
        w0[4]=(short)f2bf(f1.x); w0[5]=(short)f2bf(f1.y); w0[6]=(short)f2bf(f1.z); w0[7]=(short)f2bf(f1.w);
        w1[0]=(short)f2bf(f2.x); w1[1]=(short)f2bf(f2.y); w1[2]=(short)f2bf(f2.z); w1[3]=(short)f2bf(f2.w);
        w1[4]=(short)f2bf(f3.x); w1[5]=(short)f2bf(f3.y); w1[6]=(short)f2bf(f3.z); w1[7]=(short)f2bf(f3.w);
        *(short8*)&Alds[row * 40 + seg * 16]     = w0;
        *(short8*)&Alds[row * 40 + seg * 16 + 8] = w1;
        // stage B: bf16 direct
        const short8* bp = (const short8*)(srcB + k0 + seg * 16);
        short8 b0 = bp[0], b1 = bp[1];
        *(short8*)&Blds[row * 40 + seg * 16]     = b0;
        *(short8*)&Blds[row * 40 + seg * 16 + 8] = b1;
        __syncthreads();

        short8 af[4];
        #pragma unroll
        for (int i = 0; i < 4; ++i)
            af[i] = *(const short8*)&Alds[(wr * 64 + i * 16 + ln) * 40 + quad * 8];
        #pragma unroll
        for (int j = 0; j < 4; ++j) {
            short8 bf = *(const short8*)&Blds[(wc * 64 + j * 16 + ln) * 40 + quad * 8];
            #pragma unroll
            for (int i = 0; i < 4; ++i)
                acc[i][j] = __builtin_amdgcn_mfma_f32_16x16x32_bf16(af[i], bf, acc[i][j], 0, 0, 0);
        }
        __syncthreads();
    }

    float* dst = partial + (size_t)by * MPAD * 128;
    #pragma unroll
    for (int i = 0; i < 4; ++i) {
        #pragma unroll
        for (int j = 0; j < 4; ++j) {
            int rowb = m0 + wr * 64 + i * 16 + quad * 4;
            int col = wc * 64 + j * 16 + ln;
            #pragma unroll
            for (int r = 0; r < 4; ++r)
                dst[(size_t)(rowb + r) * 128 + col] = acc[i][j][r];
        }
    }
}

// ---------------------------------------------------------------- reduce K-slices + tanh + mask
__global__ __launch_bounds__(128) void reduce_tanh(const float* __restrict__ partial,
                                                   float* __restrict__ xe,
                                                   float* __restrict__ ae,
                                                   float* __restrict__ maskg) {
    int row = blockIdx.x;   // 0..3231
    int e = threadIdx.x;
    float s = 0.f;
    #pragma unroll
    for (int ks = 0; ks < KS; ++ks)
        s += partial[((size_t)ks * MPAD + row) * 128 + e];
    float v = fast_tanh(s);
    if (row < 3200) {
        xe[(size_t)row * 128 + e] = v;
        __shared__ int any;
        if (e == 0) any = 0;
        __syncthreads();
        if (v != 0.f) any = 1;
        __syncthreads();
        if (e == 0) maskg[row] = any ? 1.f : 0.f;
    } else {
        ae[(row - 3200) * 128 + e] = v;
    }
}

// ---------------------------------------------------------------- x_proj = xe @ gru_k + b_i   [3200][384]
__global__ __launch_bounds__(384) void xproj_kernel(const float* __restrict__ xe,
                                                    const float* __restrict__ gru_k,
                                                    const float* __restrict__ b_i,
                                                    float* __restrict__ xproj) {
    __shared__ float xs[16 * 128];
    int tid = threadIdx.x;
    int row0 = blockIdx.x * 16;
    const float4v* src = (const float4v*)(xe + (size_t)row0 * 128);
    float4v* dstl = (float4v*)xs;
    #pragma unroll
    for (int c = 0; c < 2; ++c) {
        int i4 = c * 384 + tid;
        if (i4 < 512) dstl[i4] = src[i4];
    }
    __syncthreads();
    int j = tid;  // 0..383
    float acc[16];
    #pragma unroll
    for (int r = 0; r < 16; ++r) acc[r] = 0.f;
    float bi = b_i[j];
    for (int k4 = 0; k4 < 32; ++k4) {
        float g0 = gru_k[(k4 * 4 + 0) * 384 + j];
        float g1 = gru_k[(k4 * 4 + 1) * 384 + j];
        float g2 = gru_k[(k4 * 4 + 2) * 384 + j];
        float g3 = gru_k[(k4 * 4 + 3) * 384 + j];
        #pragma unroll
        for (int r = 0; r < 16; ++r) {
            float4v xv = *(const float4v*)&xs[r * 128 + k4 * 4];
            acc[r] = fmaf(xv.x, g0, acc[r]);
            acc[r] = fmaf(xv.y, g1, acc[r]);
            acc[r] = fmaf(xv.z, g2, acc[r]);
            acc[r] = fmaf(xv.w, g3, acc[r]);
        }
    }
    #pragma unroll
    for (int r = 0; r < 16; ++r)
        xproj[(size_t)(row0 + r) * 384 + j] = acc[r] + bi;
}

// ---------------------------------------------------------------- GRU scan: 1 block / batch
__global__ __launch_bounds__(384) void gru_kernel(const float* __restrict__ xproj,
                                                  const float* __restrict__ maskg,
                                                  const float* __restrict__ gru_rk,
                                                  const float* __restrict__ b_r,
                                                  float* __restrict__ hout) {
    int b = blockIdx.x;
    int j = threadIdx.x;  // 0..383
    float w[128];
    #pragma unroll
    for (int k = 0; k < 128; ++k) w[k] = gru_rk[k * 384 + j];
    float br = b_r[j];
    __shared__ float4v hs4[32];
    __shared__ float xps[384];
    __shared__ float recs[384];
    float* hs = (float*)hs4;
    float hreg = 0.f;
    if (j < 128) hs[j] = 0.f;
    __syncthreads();
    const float* xp_base = xproj + (size_t)b * 100 * 384;
    const float* mk = maskg + b * 100;
    for (int t = 0; t < 100; ++t) {
        float xp = xp_base[t * 384 + j];
        float s0 = 0.f, s1 = 0.f, s2 = 0.f, s3 = 0.f;
        #pragma unroll
        for (int k4 = 0; k4 < 32; ++k4) {
            float4v hv = hs4[k4];
            s0 = fmaf(hv.x, w[k4 * 4 + 0], s0);
            s1 = fmaf(hv.y, w[k4 * 4 + 1], s1);
            s2 = fmaf(hv.z, w[k4 * 4 + 2], s2);
            s3 = fmaf(hv.w, w[k4 * 4 + 3], s3);
        }
        float rec = br + ((s0 + s1) + (s2 + s3));
        xps[j] = xp;
        recs[j] = rec;
        __syncthreads();
        if (j < 128) {
            float z = sigmoidf_(xps[j] + recs[j]);
            float r = sigmoidf_(xps[128 + j] + recs[128 + j]);
            float hh = fast_tanh(xps[256 + j] + r * recs[256 + j]);
            float hn = z * hreg + (1.f - z) * hh;
            float m = mk[t];
            hreg = (m != 0.f) ? hn : hreg;
            hs[j] = hreg;
        }
        __syncthreads();
    }
    if (j < 128) hout[b * 128 + j] = hreg;
}

// ---------------------------------------------------------------- head: c = tanh([h,ae]@W1+b1); out = sig([c,d]@W2+b2)
__global__ __launch_bounds__(64) void head_kernel(const float* __restrict__ hout,
                                                  const float* __restrict__ ae,
                                                  const float* __restrict__ d,
                                                  const float* __restrict__ W1,
                                                  const float* __restrict__ b1,
                                                  const float* __restrict__ W2,
                                                  const float* __restrict__ b2,
                                                  float* __restrict__ out) {
    int b = blockIdx.x;
    int m = threadIdx.x;  // 0..63
    float s = b1[m];
    const float* hb = hout + b * 128;
    const float* ab = ae + b * 128;
    #pragma unroll 4
    for (int k = 0; k < 128; ++k) s = fmaf(hb[k], W1[k * 64 + m], s);
    #pragma unroll 4
    for (int k = 0; k < 128; ++k) s = fmaf(ab[k], W1[(128 + k) * 64 + m], s);
    float c = fast_tanh(s);
    float p = c * W2[m];
    #pragma unroll
    for (int off = 32; off > 0; off >>= 1) p += __shfl_down(p, off);
    if (m == 0) {
        p += d[b * 2 + 0] * W2[64] + d[b * 2 + 1] * W2[65] + b2[0];
        out[b] = sigmoidf_(p);
    }
}

extern "C" void kernel_launch(void* const* d_in, const int* in_sizes, int n_in,
                              void* d_out, int out_size, void* d_ws, size_t ws_size,
                              hipStream_t stream) {
    (void)in_sizes; (void)n_in; (void)out_size; (void)ws_size;
    const float* x      = (const float*)d_in[0];
    const float* a      = (const float*)d_in[1];
    const float* d      = (const float*)d_in[2];
    const float* emb    = (const float*)d_in[3];
    const float* gru_k  = (const float*)d_in[4];
    const float* gru_rk = (const float*)d_in[5];
    const float* gbi    = (const float*)d_in[6];
    const float* gbr    = (const float*)d_in[7];
    const float* W1     = (const float*)d_in[8];
    const float* b1     = (const float*)d_in[9];
    const float* W2     = (const float*)d_in[10];
    const float* b2     = (const float*)d_in[11];
    float* out = (float*)d_out;

    char* ws = (char*)d_ws;
    unsigned short* embT = (unsigned short*)(ws);                 //  5,120,000 B
    float* partial = (float*)(ws + 5120000);                      // 13,631,488 B
    float* xe      = (float*)(ws + 18751488);                     //  1,638,400 B
    float* ae      = (float*)(ws + 20389888);                     //     16,384 B
    float* maskg   = (float*)(ws + 20406272);                     //     12,800 B
    float* xproj   = (float*)(ws + 20419072);                     //  4,915,200 B
    float* hout    = (float*)(ws + 25334272);                     //     16,384 B

    hipLaunchKernelGGL(cvt_embT,    dim3(313),    dim3(256), 0, stream, emb, embT);
    hipLaunchKernelGGL(big_gemm,    dim3(26, KS), dim3(256), 0, stream, x, a, embT, partial);
    hipLaunchKernelGGL(reduce_tanh, dim3(3232),   dim3(128), 0, stream, partial, xe, ae, maskg);
    hipLaunchKernelGGL(xproj_kernel,dim3(200),    dim3(384), 0, stream, xe, gru_k, gbi, xproj);
    hipLaunchKernelGGL(gru_kernel,  dim3(32),     dim3(384), 0, stream, xproj, maskg, gru_rk, gbr, hout);
    hipLaunchKernelGGL(head_kernel, dim3(32),     dim3(64),  0, stream, hout, ae, d, W1, b1, W2, b2, out);
}

// Round 2
// 573.543 us; speedup vs baseline: 1.0374x; 1.0374x over previous
//
#include <hip/hip_runtime.h>

typedef __attribute__((ext_vector_type(8))) short short8;
typedef __attribute__((ext_vector_type(4))) float float4v;

#define V_ 20000

__device__ __forceinline__ unsigned short f2bf(float f) {
    union { float f; unsigned int u; } v; v.f = f;
    unsigned int u = v.u;
    u += 0x7fffu + ((u >> 16) & 1u);
    return (unsigned short)(u >> 16);
}

__device__ __forceinline__ float fast_tanh(float x) {
    float xc = fminf(15.f, fmaxf(-15.f, x));
    float e = __expf(2.f * xc);
    return (e - 1.f) / (e + 1.f);   // tanh(0) == 0 exactly (mask depends on it)
}

__device__ __forceinline__ float sigmoidf_(float x) {
    float xc = fminf(30.f, fmaxf(-30.f, x));
    return 1.f / (1.f + __expf(-xc));
}

#define GLL16(gp, lp) __builtin_amdgcn_global_load_lds( \
    (const __attribute__((address_space(1))) void*)(gp), \
    (__attribute__((address_space(3))) void*)(lp), 16, 0, 0)

// ---------------------------------------------------------------- cvt emb -> bf16 transposed [128n][20000k]
__global__ __launch_bounds__(256) void cvt_embT(const float* __restrict__ emb,
                                                unsigned short* __restrict__ embT) {
    __shared__ unsigned short tile[128 * 65];
    int tid = threadIdx.x;
    int k0 = blockIdx.x * 64;
    const float4v* e4 = (const float4v*)emb;
    #pragma unroll
    for (int c = 0; c < 8; ++c) {
        int l4 = c * 256 + tid;      // float4 index in 64k x 128n tile
        int k = l4 >> 5;             // 32 float4 per k-row
        int n4 = l4 & 31;
        float4v f = {0.f, 0.f, 0.f, 0.f};
        if (k0 + k < V_) f = e4[(size_t)(k0 + k) * 32 + n4];
        tile[(n4 * 4 + 0) * 65 + k] = f2bf(f.x);
        tile[(n4 * 4 + 1) * 65 + k] = f2bf(f.y);
        tile[(n4 * 4 + 2) * 65 + k] = f2bf(f.z);
        tile[(n4 * 4 + 3) * 65 + k] = f2bf(f.w);
    }
    __syncthreads();
    #pragma unroll
    for (int c = 0; c < 4; ++c) {
        int l8 = c * 256 + tid;      // n*8 + seg
        int n = l8 >> 3, seg = l8 & 7;
        int kk = k0 + seg * 8;
        if (kk < V_) {
            short8 v;
            #pragma unroll
            for (int i = 0; i < 8; ++i) v[i] = (short)tile[n * 65 + seg * 8 + i];
            *(short8*)(embT + (size_t)n * V_ + kk) = v;
        }
    }
}

// ---------------------------------------------------------------- big GEMM: partial[ks][3328][128] = rows @ emb
// rows 0..3199 = x, 3200..3231 = a, rest padding. Double-buffered LDS,
// B staged via global_load_lds DMA (unpadded layout), A prefetched in regs.
__global__ __launch_bounds__(256, 4) void big_gemm(const float* __restrict__ x,
                                                   const float* __restrict__ a,
                                                   const unsigned short* __restrict__ embT,
                                                   float* __restrict__ partial,
                                                   int ks) {
    __shared__ unsigned short Alds[2][128 * 40];   // bf16, padded stride 40
    __shared__ unsigned short Blds[2][128 * 32];   // bf16, unpadded (DMA target)
    int tid = threadIdx.x;
    int bx = blockIdx.x, by = blockIdx.y;
    int m0 = bx * 128;
    int per = 625 / ks, extra = 625 % ks;
    int kb0 = by * per + (by < extra ? by : extra);
    int nkb = per + (by < extra ? 1 : 0);

    int lane = tid & 63, wave = tid >> 6;
    int wr = wave >> 1, wc = wave & 1;
    int ln = lane & 15, quad = lane >> 4;

    float4v acc[4][4];
    #pragma unroll
    for (int i = 0; i < 4; ++i)
        #pragma unroll
        for (int j = 0; j < 4; ++j) acc[i][j] = (float4v){0.f, 0.f, 0.f, 0.f};

    int row = tid >> 1, seg = tid & 1;
    int rg = m0 + row;
    int aidx = rg - 3200; aidx = aidx < 0 ? 0 : (aidx > 31 ? 31 : aidx);
    const float* __restrict__ srcA = (rg < 3200) ? (x + (size_t)rg * V_)
                                                 : (a + (size_t)aidx * V_);
    // B DMA mapping: call q in {0,1}: chunk c = q*256 + tid; brow=c>>2, bkq=c&3
    int brow0 = tid >> 2, bkq = tid & 3;
    int wbase = tid & ~63;                     // wave-uniform chunk base (q=0)
    const unsigned short* gB0 = embT + (size_t)brow0 * V_ + bkq * 8;
    const unsigned short* gB1 = embT + (size_t)(64 + brow0) * V_ + bkq * 8;

    float4v fa0, fa1, fa2, fa3;

    // ---- prologue: stage tile 0 into buf 0
    {
        int k0 = kb0 * 32;
        const float4v* ap = (const float4v*)(srcA + k0 + seg * 16);
        fa0 = ap[0]; fa1 = ap[1]; fa2 = ap[2]; fa3 = ap[3];
        GLL16(gB0 + k0, &Blds[0][(size_t)wbase * 8]);
        GLL16(gB1 + k0, &Blds[0][(size_t)(256 + wbase) * 8]);
        short8 w0, w1;
        w0[0]=(short)f2bf(fa0.x); w0[1]=(short)f2bf(fa0.y); w0[2]=(short)f2bf(fa0.z); w0[3]=(short)f2bf(fa0.w);
        w0[4]=(short)f2bf(fa1.x); w0[5]=(short)f2bf(fa1.y); w0[6]=(short)f2bf(fa1.z); w0[7]=(short)f2bf(fa1.w);
        w1[0]=(short)f2bf(fa2.x); w1[1]=(short)f2bf(fa2.y); w1[2]=(short)f2bf(fa2.z); w1[3]=(short)f2bf(fa2.w);
        w1[4]=(short)f2bf(fa3.x); w1[5]=(short)f2bf(fa3.y); w1[6]=(short)f2bf(fa3.z); w1[7]=(short)f2bf(fa3.w);
        *(short8*)&Alds[0][row * 40 + seg * 16]     = w0;
        *(short8*)&Alds[0][row * 40 + seg * 16 + 8] = w1;
    }
    __syncthreads();

    for (int it = 0; it < nkb; ++it) {
        int buf = it & 1, nxt = buf ^ 1;
        bool more = (it + 1 < nkb);
        if (more) {
            int k0 = (kb0 + it + 1) * 32;
            const float4v* ap = (const float4v*)(srcA + k0 + seg * 16);
            fa0 = ap[0]; fa1 = ap[1]; fa2 = ap[2]; fa3 = ap[3];
            GLL16(gB0 + k0, &Blds[nxt][(size_t)wbase * 8]);
            GLL16(gB1 + k0, &Blds[nxt][(size_t)(256 + wbase) * 8]);
        }
        short8 af[4];
        #pragma unroll
        for (int i = 0; i < 4; ++i)
            af[i] = *(const short8*)&Alds[buf][(wr * 64 + i * 16 + ln) * 40 + quad * 8];
        #pragma unroll
        for (int j = 0; j < 4; ++j) {
            short8 bf = *(const short8*)&Blds[buf][(wc * 64 + j * 16 + ln) * 32 + quad * 8];
            #pragma unroll
            for (int i = 0; i < 4; ++i)
                acc[i][j] = __builtin_amdgcn_mfma_f32_16x16x32_bf16(af[i], bf, acc[i][j], 0, 0, 0);
        }
        if (more) {
            short8 w0, w1;
            w0[0]=(short)f2bf(fa0.x); w0[1]=(short)f2bf(fa0.y); w0[2]=(short)f2bf(fa0.z); w0[3]=(short)f2bf(fa0.w);
            w0[4]=(short)f2bf(fa1.x); w0[5]=(short)f2bf(fa1.y); w0[6]=(short)f2bf(fa1.z); w0[7]=(short)f2bf(fa1.w);
            w1[0]=(short)f2bf(fa2.x); w1[1]=(short)f2bf(fa2.y); w1[2]=(short)f2bf(fa2.z); w1[3]=(short)f2bf(fa2.w);
            w1[4]=(short)f2bf(fa3.x); w1[5]=(short)f2bf(fa3.y); w1[6]=(short)f2bf(fa3.z); w1[7]=(short)f2bf(fa3.w);
            *(short8*)&Alds[nxt][row * 40 + seg * 16]     = w0;
            *(short8*)&Alds[nxt][row * 40 + seg * 16 + 8] = w1;
        }
        __syncthreads();
    }

    float* dst = partial + (size_t)by * 3328 * 128;
    #pragma unroll
    for (int i = 0; i < 4; ++i) {
        #pragma unroll
        for (int j = 0; j < 4; ++j) {
            int rowb = m0 + wr * 64 + i * 16 + quad * 4;
            int col = wc * 64 + j * 16 + ln;
            #pragma unroll
            for (int r = 0; r < 4; ++r)
                dst[(size_t)(rowb + r) * 128 + col] = acc[i][j][r];
        }
    }
}

// ---------------------------------------------------------------- reduce K-slices + tanh + mask
__global__ __launch_bounds__(128) void reduce_tanh(const float* __restrict__ partial,
                                                   float* __restrict__ xe,
                                                   float* __restrict__ ae,
                                                   float* __restrict__ maskg,
                                                   int ks) {
    int row = blockIdx.x;   // 0..3231
    int e = threadIdx.x;
    float s = 0.f;
    for (int k = 0; k < ks; ++k)
        s += partial[((size_t)k * 3328 + row) * 128 + e];
    float v = fast_tanh(s);
    if (row < 3200) {
        xe[(size_t)row * 128 + e] = v;
        __shared__ int any;
        if (e == 0) any = 0;
        __syncthreads();
        if (v != 0.f) any = 1;
        __syncthreads();
        if (e == 0) maskg[row] = any ? 1.f : 0.f;
    } else {
        ae[(row - 3200) * 128 + e] = v;
    }
}

// ---------------------------------------------------------------- x_proj = xe @ gru_k + b_i   [3200][384]
__global__ __launch_bounds__(384) void xproj_kernel(const float* __restrict__ xe,
                                                    const float* __restrict__ gru_k,
                                                    const float* __restrict__ b_i,
                                                    float* __restrict__ xproj) {
    __shared__ float xs[16 * 128];
    int tid = threadIdx.x;
    int row0 = blockIdx.x * 16;
    const float4v* src = (const float4v*)(xe + (size_t)row0 * 128);
    float4v* dstl = (float4v*)xs;
    #pragma unroll
    for (int c = 0; c < 2; ++c) {
        int i4 = c * 384 + tid;
        if (i4 < 512) dstl[i4] = src[i4];
    }
    __syncthreads();
    int j = tid;  // 0..383
    float acc[16];
    #pragma unroll
    for (int r = 0; r < 16; ++r) acc[r] = 0.f;
    float bi = b_i[j];
    for (int k4 = 0; k4 < 32; ++k4) {
        float g0 = gru_k[(k4 * 4 + 0) * 384 + j];
        float g1 = gru_k[(k4 * 4 + 1) * 384 + j];
        float g2 = gru_k[(k4 * 4 + 2) * 384 + j];
        float g3 = gru_k[(k4 * 4 + 3) * 384 + j];
        #pragma unroll
        for (int r = 0; r < 16; ++r) {
            float4v xv = *(const float4v*)&xs[r * 128 + k4 * 4];
            acc[r] = fmaf(xv.x, g0, acc[r]);
            acc[r] = fmaf(xv.y, g1, acc[r]);
            acc[r] = fmaf(xv.z, g2, acc[r]);
            acc[r] = fmaf(xv.w, g3, acc[r]);
        }
    }
    #pragma unroll
    for (int r = 0; r < 16; ++r)
        xproj[(size_t)(row0 + r) * 384 + j] = acc[r] + bi;
}

// ---------------------------------------------------------------- GRU scan: 1 block / batch
__global__ __launch_bounds__(384) void gru_kernel(const float* __restrict__ xproj,
                                                  const float* __restrict__ maskg,
                                                  const float* __restrict__ gru_rk,
                                                  const float* __restrict__ b_r,
                                                  float* __restrict__ hout) {
    int b = blockIdx.x;
    int j = threadIdx.x;  // 0..383
    float w[128];
    #pragma unroll
    for (int k = 0; k < 128; ++k) w[k] = gru_rk[k * 384 + j];
    float br = b_r[j];
    __shared__ float4v hs4[32];
    __shared__ float recs[384];
    float* hs = (float*)hs4;
    float hreg = 0.f;
    if (j < 128) hs[j] = 0.f;
    const float* xp_base = xproj + (size_t)b * 100 * 384;
    const float* mk = maskg + b * 100;
    // prefetched gate inputs for j<128 threads
    float xz = 0.f, xr = 0.f, xh = 0.f;
    if (j < 128) { xz = xp_base[j]; xr = xp_base[128 + j]; xh = xp_base[256 + j]; }
    __syncthreads();
    for (int t = 0; t < 100; ++t) {
        // prefetch next step's gate inputs (latency hidden behind matvec + gates)
        float nxz = 0.f, nxr = 0.f, nxh = 0.f;
        if (t < 99 && j < 128) {
            const float* nb = xp_base + (t + 1) * 384;
            nxz = nb[j]; nxr = nb[128 + j]; nxh = nb[256 + j];
        }
        float s0 = 0.f, s1 = 0.f, s2 = 0.f, s3 = 0.f;
        #pragma unroll
        for (int k4 = 0; k4 < 32; ++k4) {
            float4v hv = hs4[k4];
            s0 = fmaf(hv.x, w[k4 * 4 + 0], s0);
            s1 = fmaf(hv.y, w[k4 * 4 + 1], s1);
            s2 = fmaf(hv.z, w[k4 * 4 + 2], s2);
            s3 = fmaf(hv.w, w[k4 * 4 + 3], s3);
        }
        recs[j] = br + ((s0 + s1) + (s2 + s3));
        __syncthreads();
        if (j < 128) {
            float z = sigmoidf_(xz + recs[j]);
            float r = sigmoidf_(xr + recs[128 + j]);
            float hh = fast_tanh(xh + r * recs[256 + j]);
            float hn = z * hreg + (1.f - z) * hh;
            hreg = (mk[t] != 0.f) ? hn : hreg;
            hs[j] = hreg;
        }
        __syncthreads();
        xz = nxz; xr = nxr; xh = nxh;
    }
    if (j < 128) hout[b * 128 + j] = hreg;
}

// ---------------------------------------------------------------- head
__global__ __launch_bounds__(64) void head_kernel(const float* __restrict__ hout,
                                                  const float* __restrict__ ae,
                                                  const float* __restrict__ d,
                                                  const float* __restrict__ W1,
                                                  const float* __restrict__ b1,
                                                  const float* __restrict__ W2,
                                                  const float* __restrict__ b2,
                                                  float* __restrict__ out) {
    int b = blockIdx.x;
    int m = threadIdx.x;  // 0..63
    float s = b1[m];
    const float* hb = hout + b * 128;
    const float* ab = ae + b * 128;
    #pragma unroll 4
    for (int k = 0; k < 128; ++k) s = fmaf(hb[k], W1[k * 64 + m], s);
    #pragma unroll 4
    for (int k = 0; k < 128; ++k) s = fmaf(ab[k], W1[(128 + k) * 64 + m], s);
    float c = fast_tanh(s);
    float p = c * W2[m];
    #pragma unroll
    for (int off = 32; off > 0; off >>= 1) p += __shfl_down(p, off);
    if (m == 0) {
        p += d[b * 2 + 0] * W2[64] + d[b * 2 + 1] * W2[65] + b2[0];
        out[b] = sigmoidf_(p);
    }
}

extern "C" void kernel_launch(void* const* d_in, const int* in_sizes, int n_in,
                              void* d_out, int out_size, void* d_ws, size_t ws_size,
                              hipStream_t stream) {
    (void)in_sizes; (void)n_in; (void)out_size;
    const float* x      = (const float*)d_in[0];
    const float* a      = (const float*)d_in[1];
    const float* d      = (const float*)d_in[2];
    const float* emb    = (const float*)d_in[3];
    const float* gru_k  = (const float*)d_in[4];
    const float* gru_rk = (const float*)d_in[5];
    const float* gbi    = (const float*)d_in[6];
    const float* gbr    = (const float*)d_in[7];
    const float* W1     = (const float*)d_in[8];
    const float* b1     = (const float*)d_in[9];
    const float* W2     = (const float*)d_in[10];
    const float* b2     = (const float*)d_in[11];
    float* out = (float*)d_out;

    char* ws = (char*)d_ws;
    unsigned short* embT = (unsigned short*)(ws);              //  5,120,000 B
    float* xe      = (float*)(ws + 5120000);                   //  1,638,400 B
    float* ae      = (float*)(ws + 6758400);                   //     16,384 B
    float* maskg   = (float*)(ws + 6774784);                   //     12,800 B
    float* xproj   = (float*)(ws + 6787584);                   //  4,915,200 B
    float* hout    = (float*)(ws + 11702784);                  //     16,384 B
    const size_t fixed = 11719168;
    const size_t slice = (size_t)3328 * 128 * 4;               //  1,703,936 B
    float* partial = (float*)(ws + fixed);

    // runtime split-K factor: as many K-slices as the workspace allows (cap 32)
    int ks = 8;
    if (ws_size > fixed + slice) {
        size_t avail = (ws_size - fixed) / slice;
        ks = (int)(avail < 32 ? avail : 32);
        if (ks < 1) ks = 1;
    }

    hipLaunchKernelGGL(cvt_embT,    dim3(313),     dim3(256), 0, stream, emb, embT);
    hipLaunchKernelGGL(big_gemm,    dim3(26, ks),  dim3(256), 0, stream, x, a, embT, partial, ks);
    hipLaunchKernelGGL(reduce_tanh, dim3(3232),    dim3(128), 0, stream, partial, xe, ae, maskg, ks);
    hipLaunchKernelGGL(xproj_kernel,dim3(200),     dim3(384), 0, stream, xe, gru_k, gbi, xproj);
    hipLaunchKernelGGL(gru_kernel,  dim3(32),      dim3(384), 0, stream, xproj, maskg, gru_rk, gbr, hout);
    hipLaunchKernelGGL(head_kernel, dim3(32),      dim3(64),  0, stream, hout, ae, d, W1, b1, W2, b2, out);
}